// Round 10
// baseline (70.790 us; speedup 1.0000x reference)
//
#include <hip/hip_runtime.h>
#include <stdint.h>

// ---- problem constants ----
constexpr int NB   = 4;      // batch
constexpr int CIN  = 3;
constexpr int HIN  = 256;
constexpr int COUT = 256;
constexpr int HF   = 128;              // feature H=W after stride-2 conv
constexpr int NF   = HF * HF;          // 16384
constexpr int KADM = 16;
constexpr int KK   = KADM * KADM;      // 256 descriptors
constexpr int HID  = 128;              // MLP hidden
constexpr int DFB  = 65536;            // desc-fragment u16s per batch
constexpr int PX   = 32;               // pixels per fused block
constexpr int NT   = NF / PX;          // 512 tiles per batch

typedef unsigned short ushort_t;
typedef __attribute__((ext_vector_type(8))) _Float16 f16x8;
typedef __attribute__((ext_vector_type(4))) float    f32x4;

__device__ inline unsigned long long shfl_xor_u64(unsigned long long v, int m) {
    unsigned lo = __shfl_xor((unsigned)v, m, 64);
    unsigned hi = __shfl_xor((unsigned)(v >> 32), m, 64);
    return ((unsigned long long)hi << 32) | lo;
}
__device__ inline unsigned long long shfl_down_u64(unsigned long long v, int off) {
    unsigned lo = __shfl_down((unsigned)v, off, 64);
    unsigned hi = __shfl_down((unsigned)(v >> 32), off, 64);
    return ((unsigned long long)hi << 32) | lo;
}
__device__ inline unsigned long long u64min(unsigned long long a, unsigned long long b) {
    return a < b ? a : b;
}
__device__ inline ushort_t f16bits(_Float16 h) { return __builtin_bit_cast(ushort_t, h); }

// LDS swizzle for [PX][256] f16 planes: XOR 8-f16 chunk index with pix&7.
__device__ inline int swz(int pix, int c) {
    return pix * 256 + ((((c >> 3) ^ (pix & 7)) << 3) | (c & 7));
}

// desc fragment address: [w][chunk][j][lane][8]
__device__ inline int dfoff(int w, int chunk, int j, int lane) {
    return (((w * 8 + chunk) * 4 + j) * 64 + lane) * 8;
}

// =====================================================================
// Prep: split conv weights into f16 hi/lo, K padded 27->32, stored in
// MFMA B-fragment order keyed by (w,j): co = w*64 + j*16 + la.
// =====================================================================
__global__ __launch_bounds__(256) void prep_kernel(
        const float* __restrict__ W, ushort_t* __restrict__ WFh, ushort_t* __restrict__ WFl)
{
    int co = threadIdx.x;
    int w = co >> 6, j = (co >> 4) & 3, la = co & 15;
    #pragma unroll
    for (int q = 0; q < 32; ++q) {
        float v = (q < 27) ? W[co * 27 + q] : 0.f;
        _Float16 h = (_Float16)v;
        _Float16 l = (_Float16)(v - (float)h);
        int lg = q >> 3, e = q & 7;
        int off = ((w * 4 + j) * 64 + lg * 16 + la) * 8 + e;
        WFh[off] = f16bits(h);
        WFl[off] = f16bits(l);
    }
}

// =====================================================================
// Conv-A: MFMA im2col conv, emits resp = sum_c relu(v) only (64-px tiles).
// =====================================================================
__global__ __launch_bounds__(256) void convA_kernel(
        const float* __restrict__ xA,
        const ushort_t* __restrict__ WFh, const ushort_t* __restrict__ WFl,
        const float* __restrict__ bias, float* __restrict__ resp)
{
    __shared__ float    pS[CIN][3][132];
    __shared__ ushort_t Ah[64][40];
    __shared__ ushort_t Al[64][40];
    __shared__ float    redS[4][64];

    int tile = blockIdx.x;
    int b    = blockIdx.y;
    int oh   = tile >> 1;
    int ow0  = (tile & 1) << 6;
    const float* x = xA + (size_t)b * CIN * HIN * HIN;
    int tid = threadIdx.x;

    for (int i = tid; i < CIN * 3 * 129; i += 256) {
        int ci = i / (3 * 129);
        int r2 = i % (3 * 129);
        int kh = r2 / 129, c = r2 % 129;
        int gr = 2 * oh - 1 + kh, gc = 2 * ow0 - 1 + c;
        float v = 0.f;
        if (gr >= 0 && gr < HIN && gc >= 0 && gc < HIN)
            v = x[(size_t)ci * HIN * HIN + (size_t)gr * HIN + gc];
        pS[ci][kh][c] = v;
    }
    __syncthreads();

    {
        int n = tid >> 2, qg = tid & 3;
        unsigned uh[4], ul[4];
        #pragma unroll
        for (int e2 = 0; e2 < 4; ++e2) {
            ushort_t hh[2], ll[2];
            #pragma unroll
            for (int s = 0; s < 2; ++s) {
                int q = qg * 8 + e2 * 2 + s;
                float v = 0.f;
                if (q < 27) {
                    int ci = q / 9, r = (q % 9) / 3, kw = q % 3;
                    v = pS[ci][r][2 * n + kw];
                }
                _Float16 h = (_Float16)v;
                _Float16 l = (_Float16)(v - (float)h);
                hh[s] = f16bits(h); ll[s] = f16bits(l);
            }
            uh[e2] = (unsigned)hh[0] | ((unsigned)hh[1] << 16);
            ul[e2] = (unsigned)ll[0] | ((unsigned)ll[1] << 16);
        }
        *(uint4*)&Ah[n][qg * 8] = *(uint4*)uh;
        *(uint4*)&Al[n][qg * 8] = *(uint4*)ul;
    }
    __syncthreads();

    int lane = tid & 63, w = tid >> 6;
    int la = lane & 15, lg = lane >> 4;
    int wbase = w * 64;

    float bj[4];
    #pragma unroll
    for (int j = 0; j < 4; ++j) bj[j] = bias[wbase + j * 16 + la];

    f16x8 ah[4], al[4], bh[4], bl[4];
    #pragma unroll
    for (int i = 0; i < 4; ++i) {
        ah[i] = *(const f16x8*)&Ah[i * 16 + la][lg * 8];
        al[i] = *(const f16x8*)&Al[i * 16 + la][lg * 8];
    }
    #pragma unroll
    for (int j = 0; j < 4; ++j) {
        int off = ((w * 4 + j) * 64 + lane) * 8;
        bh[j] = *(const f16x8*)&WFh[off];
        bl[j] = *(const f16x8*)&WFl[off];
    }

    f32x4 acc[4][4];
    #pragma unroll
    for (int i = 0; i < 4; ++i)
        #pragma unroll
        for (int j = 0; j < 4; ++j) acc[i][j] = (f32x4)0.f;

    #pragma unroll
    for (int i = 0; i < 4; ++i)
        #pragma unroll
        for (int j = 0; j < 4; ++j) {
            acc[i][j] = __builtin_amdgcn_mfma_f32_16x16x32_f16(ah[i], bh[j], acc[i][j], 0, 0, 0);
            acc[i][j] = __builtin_amdgcn_mfma_f32_16x16x32_f16(al[i], bh[j], acc[i][j], 0, 0, 0);
            acc[i][j] = __builtin_amdgcn_mfma_f32_16x16x32_f16(ah[i], bl[j], acc[i][j], 0, 0, 0);
        }

    float s[4][4];
    #pragma unroll
    for (int i = 0; i < 4; ++i)
        #pragma unroll
        for (int r = 0; r < 4; ++r) s[i][r] = 0.f;

    #pragma unroll
    for (int i = 0; i < 4; ++i)
        #pragma unroll
        for (int j = 0; j < 4; ++j)
            #pragma unroll
            for (int r = 0; r < 4; ++r)
                s[i][r] += fmaxf(acc[i][j][r] + bj[j], 0.f);

    #pragma unroll
    for (int i = 0; i < 4; ++i)
        #pragma unroll
        for (int r = 0; r < 4; ++r) {
            float v = s[i][r];
            v += __shfl_xor(v, 1, 64);
            v += __shfl_xor(v, 2, 64);
            v += __shfl_xor(v, 4, 64);
            v += __shfl_xor(v, 8, 64);
            s[i][r] = v;
        }
    if (la == 0) {
        #pragma unroll
        for (int i = 0; i < 4; ++i)
            #pragma unroll
            for (int r = 0; r < 4; ++r)
                redS[w][i * 16 + lg * 4 + r] = s[i][r];
    }
    __syncthreads();
    if (tid < 64) {
        float tot = redS[0][tid] + redS[1][tid] + redS[2][tid] + redS[3][tid];
        resp[(size_t)b * NF + oh * HF + ow0 + tid] = tot;
    }
}

// =====================================================================
// Fused select: pool argmax (wave 0) + descriptor conv-recompute (fp32).
// Writes desc in MFMA B-fragment order: dFh/dFl[b][w][chunk][j][lane][8].
// =====================================================================
__global__ __launch_bounds__(256) void select_kernel(
        const float* __restrict__ resp,
        const float* __restrict__ xA, const float* __restrict__ W,
        const float* __restrict__ bias,
        int* __restrict__ idxA,
        ushort_t* __restrict__ dFh, ushort_t* __restrict__ dFl,
        float* __restrict__ normA)
{
    __shared__ float patch[27];
    __shared__ float red[4];
    __shared__ int   sidx;

    int bk = blockIdx.x;              // b*KK + k
    int b = bk >> 8, k = bk & 255;
    int t = threadIdx.x;              // channel c

    if (t < 64) {
        int kr = k >> 4, kc = k & 15;
        int lr = t >> 3, lc = t & 7;
        int row = kr * 8 + lr, col = kc * 8 + lc;
        float bv = resp[(size_t)b * NF + (size_t)row * HF + col];
        int best = t;
        for (int off = 32; off > 0; off >>= 1) {
            float ov = __shfl_down(bv, off, 64);
            int   oi = __shfl_down(best, off, 64);
            if (ov > bv || (ov == bv && oi < best)) { bv = ov; best = oi; }
        }
        if (t == 0) {
            int r = kr * 8 + (best >> 3), c = kc * 8 + (best & 7);
            int idx = r * HF + c;
            idxA[bk] = idx;
            sidx = idx;
        }
    }
    __syncthreads();
    int idx = sidx;
    int oh = idx >> 7, ow = idx & 127;

    if (t < 27) {
        int ci = t / 9, kh = (t % 9) / 3, kw = t % 3;
        int ir = oh * 2 - 1 + kh, ic = ow * 2 - 1 + kw;
        float v = 0.f;
        if (ir >= 0 && ir < HIN && ic >= 0 && ic < HIN)
            v = xA[((size_t)b * CIN + ci) * HIN * HIN + (size_t)ir * HIN + ic];
        patch[t] = v;
    }
    __syncthreads();

    float v = bias[t];
    const float* w = &W[t * 27];
    #pragma unroll
    for (int q = 0; q < 27; ++q) v = fmaf(patch[q], w[q], v);
    v = fmaxf(v, 0.f);

    _Float16 h = (_Float16)v;
    _Float16 l = (_Float16)(v - (float)h);
    {
        int wq = k >> 6, j = (k >> 4) & 3, la = k & 15;
        int chunk = t >> 5, lg = (t >> 3) & 3, e = t & 7;
        int off = b * DFB + dfoff(wq, chunk, j, lg * 16 + la) + e;
        dFh[off] = f16bits(h);
        dFl[off] = f16bits(l);
    }

    float s = v * v;
    for (int off = 32; off > 0; off >>= 1) s += __shfl_down(s, off, 64);
    if ((t & 63) == 0) red[t >> 6] = s;
    __syncthreads();
    if (t == 0) normA[bk] = red[0] + red[1] + red[2] + red[3];
}

// ---- fused-kernel helpers ----
__device__ inline void load_desc(const ushort_t* __restrict__ dFh,
                                 const ushort_t* __restrict__ dFl,
                                 int w, int chunk, int lane,
                                 f16x8* bh, f16x8* bl)
{
    #pragma unroll
    for (int j = 0; j < 4; ++j) {
        int off = dfoff(w, chunk, j, lane);
        bh[j] = *(const f16x8*)&dFh[off];
        bl[j] = *(const f16x8*)&dFl[off];
    }
}

__device__ inline void knn_chunk(const ushort_t* __restrict__ fH,
                                 const ushort_t* __restrict__ fL,
                                 int la, int lg, int cc,
                                 const f16x8* bh, const f16x8* bl,
                                 f32x4 (&acc)[2][4])
{
    #pragma unroll
    for (int i = 0; i < 2; ++i) {
        f16x8 ah = *(const f16x8*)&fH[swz(i * 16 + la, cc + lg * 8)];
        f16x8 al = *(const f16x8*)&fL[swz(i * 16 + la, cc + lg * 8)];
        __builtin_amdgcn_s_setprio(1);
        #pragma unroll
        for (int j = 0; j < 4; ++j) {
            acc[i][j] = __builtin_amdgcn_mfma_f32_16x16x32_f16(ah, bh[j], acc[i][j], 0, 0, 0);
            acc[i][j] = __builtin_amdgcn_mfma_f32_16x16x32_f16(al, bh[j], acc[i][j], 0, 0, 0);
            acc[i][j] = __builtin_amdgcn_mfma_f32_16x16x32_f16(ah, bl[j], acc[i][j], 0, 0, 0);
        }
        __builtin_amdgcn_s_setprio(0);
    }
}

// =====================================================================
// FUSED conv-B + kNN, 32-pixel blocks for 4 blocks/CU occupancy.
// =====================================================================
__global__ __launch_bounds__(256, 4) void fused_kernel(
        const float* __restrict__ xB,
        const ushort_t* __restrict__ WFh, const ushort_t* __restrict__ WFl,
        const float* __restrict__ bias,
        const ushort_t* __restrict__ dFhg, const ushort_t* __restrict__ dFlg,
        const float* __restrict__ normA,
        unsigned long long* __restrict__ scratch)
{
    __shared__ __align__(16) char smem[2 * PX * 256 * 2];   // 32768 B
    __shared__ float redS[4][PX];
    __shared__ float nAS[KK];
    __shared__ float nBS[PX];

    float*    pSp = (float*)smem;                            // [3][3][68] = 2448B
    ushort_t* AhP = (ushort_t*)(smem + 2448);                // [32][40] = 2560B
    ushort_t* AlP = (ushort_t*)(smem + 2448 + 2560);         // [32][40]
    ushort_t* fH  = (ushort_t*)smem;                         // [PX][256] swizzled
    ushort_t* fL  = (ushort_t*)(smem + PX * 256 * 2);        // [PX][256] swizzled

    int tile = blockIdx.x;           // 0..511 (n-tile)
    int b    = blockIdx.y;
    int oh   = tile >> 2;
    int ow0  = (tile & 3) << 5;
    const float* x = xB + (size_t)b * CIN * HIN * HIN;
    int tid = threadIdx.x;

    nAS[tid] = normA[b * KK + tid];

    // ---- stage input rows: 3ci x 3kh x 65 cols ----
    for (int i = tid; i < CIN * 3 * 65; i += 256) {
        int ci = i / (3 * 65);
        int r2 = i % (3 * 65);
        int kh = r2 / 65, c = r2 % 65;
        int gr = 2 * oh - 1 + kh, gc = 2 * ow0 - 1 + c;
        float v = 0.f;
        if (gr >= 0 && gr < HIN && gc >= 0 && gc < HIN)
            v = x[(size_t)ci * HIN * HIN + (size_t)gr * HIN + gc];
        pSp[ci * 204 + kh * 68 + c] = v;
    }
    __syncthreads();

    // ---- im2col: n = tid>>3 (0..31), qg = tid&7 -> q = qg*4+s ----
    {
        int n = tid >> 3, qg = tid & 7;
        ushort_t hh[4], ll[4];
        #pragma unroll
        for (int s = 0; s < 4; ++s) {
            int q = qg * 4 + s;
            float v = 0.f;
            if (q < 27) {
                int ci = q / 9, r = (q % 9) / 3, kw = q % 3;
                v = pSp[ci * 204 + r * 68 + 2 * n + kw];
            }
            _Float16 h = (_Float16)v;
            _Float16 l = (_Float16)(v - (float)h);
            hh[s] = f16bits(h); ll[s] = f16bits(l);
        }
        unsigned lo, hi;
        lo = (unsigned)hh[0] | ((unsigned)hh[1] << 16);
        hi = (unsigned)hh[2] | ((unsigned)hh[3] << 16);
        *(uint2*)&AhP[n * 40 + qg * 4] = make_uint2(lo, hi);
        lo = (unsigned)ll[0] | ((unsigned)ll[1] << 16);
        hi = (unsigned)ll[2] | ((unsigned)ll[3] << 16);
        *(uint2*)&AlP[n * 40 + qg * 4] = make_uint2(lo, hi);
    }
    __syncthreads();

    int lane = tid & 63, w = tid >> 6;
    int la = lane & 15, lg = lane >> 4;
    int wbase = w * 64;

    float bj[4];
    #pragma unroll
    for (int j = 0; j < 4; ++j) bj[j] = bias[wbase + j * 16 + la];

    // ---- conv MFMA (2 i-tiles) ----
    f16x8 cah[2], cal[2], cbh[4], cbl[4];
    #pragma unroll
    for (int i = 0; i < 2; ++i) {
        cah[i] = *(const f16x8*)&AhP[(i * 16 + la) * 40 + lg * 8];
        cal[i] = *(const f16x8*)&AlP[(i * 16 + la) * 40 + lg * 8];
    }
    #pragma unroll
    for (int j = 0; j < 4; ++j) {
        int off = ((w * 4 + j) * 64 + lane) * 8;
        cbh[j] = *(const f16x8*)&WFh[off];
        cbl[j] = *(const f16x8*)&WFl[off];
    }

    f32x4 cacc[2][4];
    #pragma unroll
    for (int i = 0; i < 2; ++i)
        #pragma unroll
        for (int j = 0; j < 4; ++j) cacc[i][j] = (f32x4)0.f;

    #pragma unroll
    for (int i = 0; i < 2; ++i)
        #pragma unroll
        for (int j = 0; j < 4; ++j) {
            cacc[i][j] = __builtin_amdgcn_mfma_f32_16x16x32_f16(cah[i], cbh[j], cacc[i][j], 0, 0, 0);
            cacc[i][j] = __builtin_amdgcn_mfma_f32_16x16x32_f16(cal[i], cbh[j], cacc[i][j], 0, 0, 0);
            cacc[i][j] = __builtin_amdgcn_mfma_f32_16x16x32_f16(cah[i], cbl[j], cacc[i][j], 0, 0, 0);
        }

    __syncthreads();   // all waves done reading AhP/AlP (aliased with fH)

    // ---- epilogue: relu, f16-split into swizzled LDS planes, sumsq ----
    float s[2][4];
    #pragma unroll
    for (int i = 0; i < 2; ++i)
        #pragma unroll
        for (int r = 0; r < 4; ++r) s[i][r] = 0.f;

    #pragma unroll
    for (int i = 0; i < 2; ++i) {
        #pragma unroll
        for (int j = 0; j < 4; ++j) {
            int co = wbase + j * 16 + la;
            #pragma unroll
            for (int r = 0; r < 4; ++r) {
                float v = fmaxf(cacc[i][j][r] + bj[j], 0.f);
                _Float16 h = (_Float16)v;
                _Float16 l = (_Float16)(v - (float)h);
                int pix = i * 16 + lg * 4 + r;
                fH[swz(pix, co)] = f16bits(h);
                fL[swz(pix, co)] = f16bits(l);
                s[i][r] = fmaf(v, v, s[i][r]);
            }
        }
    }

    // ---- early desc prefetch (cacc dead; loads fly under barrier/reduce) ----
    const ushort_t* dFh = dFhg + (size_t)b * DFB;
    const ushort_t* dFl = dFlg + (size_t)b * DFB;
    f16x8 bhA[4], blA[4], bhB[4], blB[4];
    load_desc(dFh, dFl, w, 0, lane, bhA, blA);
    load_desc(dFh, dFl, w, 1, lane, bhB, blB);

    #pragma unroll
    for (int i = 0; i < 2; ++i)
        #pragma unroll
        for (int r = 0; r < 4; ++r) {
            float v = s[i][r];
            v += __shfl_xor(v, 1, 64);
            v += __shfl_xor(v, 2, 64);
            v += __shfl_xor(v, 4, 64);
            v += __shfl_xor(v, 8, 64);
            s[i][r] = v;
        }
    if (la == 0) {
        #pragma unroll
        for (int i = 0; i < 2; ++i)
            #pragma unroll
            for (int r = 0; r < 4; ++r)
                redS[w][i * 16 + lg * 4 + r] = s[i][r];
    }
    __syncthreads();
    if (tid < PX) nBS[tid] = redS[0][tid] + redS[1][tid] + redS[2][tid] + redS[3][tid];
    __syncthreads();

    // ---- kNN: 3-pass MFMA, 2-deep desc prefetch, no barriers ----
    f32x4 acc[2][4];
    #pragma unroll
    for (int i = 0; i < 2; ++i)
        #pragma unroll
        for (int j = 0; j < 4; ++j) acc[i][j] = (f32x4)0.f;

    knn_chunk(fH, fL, la, lg, 0, bhA, blA, acc);
    load_desc(dFh, dFl, w, 2, lane, bhA, blA);
    knn_chunk(fH, fL, la, lg, 32, bhB, blB, acc);
    load_desc(dFh, dFl, w, 3, lane, bhB, blB);
    knn_chunk(fH, fL, la, lg, 64, bhA, blA, acc);
    load_desc(dFh, dFl, w, 4, lane, bhA, blA);
    knn_chunk(fH, fL, la, lg, 96, bhB, blB, acc);
    load_desc(dFh, dFl, w, 5, lane, bhB, blB);
    knn_chunk(fH, fL, la, lg, 128, bhA, blA, acc);
    load_desc(dFh, dFl, w, 6, lane, bhA, blA);
    knn_chunk(fH, fL, la, lg, 160, bhB, blB, acc);
    load_desc(dFh, dFl, w, 7, lane, bhB, blB);
    knn_chunk(fH, fL, la, lg, 192, bhA, blA, acc);
    knn_chunk(fH, fL, la, lg, 224, bhB, blB, acc);

    // ---- epilogue: dist + per-k argmin ----
    float nBv[2][4];
    #pragma unroll
    for (int i = 0; i < 2; ++i) {
        f32x4 t4 = *(const f32x4*)&nBS[i * 16 + lg * 4];
        nBv[i][0] = t4[0]; nBv[i][1] = t4[1]; nBv[i][2] = t4[2]; nBv[i][3] = t4[3];
    }
    int n0 = tile * PX;
    #pragma unroll
    for (int j = 0; j < 4; ++j) {
        int kl = wbase + j * 16 + la;
        float nAv = nAS[kl];
        unsigned long long best = ~0ull;
        #pragma unroll
        for (int i = 0; i < 2; ++i)
            #pragma unroll
            for (int r = 0; r < 4; ++r) {
                int n = n0 + i * 16 + lg * 4 + r;
                float d = fmaf(-2.f, acc[i][j][r], nAv) + nBv[i][r];
                unsigned u = __float_as_uint(d);
                u = (u & 0x80000000u) ? ~u : (u | 0x80000000u);
                unsigned long long key = ((unsigned long long)u << 32) | (unsigned)n;
                best = u64min(best, key);
            }
        best = u64min(best, shfl_xor_u64(best, 16));
        best = u64min(best, shfl_xor_u64(best, 32));
        if (lg == 0)
            scratch[(size_t)(b * KK + kl) * NT + tile] = best;
    }
}

// =====================================================================
// Final argmin reduce over the NT tiles -> minN[b*KK + k]
// =====================================================================
__global__ __launch_bounds__(64) void reduce_kernel(
        const unsigned long long* __restrict__ scratch, int* __restrict__ minN)
{
    int bk = blockIdx.x;              // b*KK + k
    int t = threadIdx.x;
    const unsigned long long* s = scratch + (size_t)bk * NT;
    unsigned long long best = ~0ull;
    #pragma unroll
    for (int m = 0; m < NT / 64; ++m)
        best = u64min(best, s[t + m * 64]);
    for (int off = 32; off > 0; off >>= 1)
        best = u64min(best, shfl_down_u64(best, off));
    if (t == 0) minN[bk] = (int)(best & 0xffffffffULL);
}

// =====================================================================
// Two tiny MLPs: x(256) -> 128 relu -> 1. block per (b, which), 128 threads.
// =====================================================================
__global__ __launch_bounds__(128) void mlp_kernel(
        const int* __restrict__ idxA, const int* __restrict__ minN,
        const float* __restrict__ W1r, const float* __restrict__ b1r,
        const float* __restrict__ W2r, const float* __restrict__ b2r,
        const float* __restrict__ W1c, const float* __restrict__ b1c,
        const float* __restrict__ W2c, const float* __restrict__ b2c,
        float* __restrict__ out)
{
    __shared__ float xS[KK];
    __shared__ float red[2];
    int blk = blockIdx.x;            // b*2 + which
    int b = blk >> 1, which = blk & 1;
    int t = threadIdx.x;             // 0..127

    for (int k = t; k < KK; k += 128) {
        int ia = idxA[b * KK + k];
        int nn = minN[b * KK + k];
        int rowA = ia >> 7, colA = ia & 127;
        int rowB = nn >> 7, colB = nn & 127;
        xS[k] = (which == 0) ? (float)(rowB - rowA) : (float)(colA - colB);
    }
    __syncthreads();

    const float* W1 = which ? W1c : W1r;
    const float* b1 = which ? b1c : b1r;
    const float* W2 = which ? W2c : W2r;
    const float* b2 = which ? b2c : b2r;

    float h = b1[t];
    for (int k = 0; k < KK; ++k) h = fmaf(xS[k], W1[k * HID + t], h);
    h = fmaxf(h, 0.f);
    float pv = h * W2[t];
    for (int off = 32; off > 0; off >>= 1) pv += __shfl_down(pv, off, 64);
    if ((t & 63) == 0) red[t >> 6] = pv;
    __syncthreads();
    if (t == 0) out[b * 2 + which] = red[0] + red[1] + b2[0];
}

// =====================================================================
extern "C" void kernel_launch(void* const* d_in, const int* in_sizes, int n_in,
                              void* d_out, int out_size, void* d_ws, size_t ws_size,
                              hipStream_t stream)
{
    const float* xA  = (const float*)d_in[0];
    const float* xB  = (const float*)d_in[1];
    const float* Wc  = (const float*)d_in[2];
    const float* bc  = (const float*)d_in[3];
    const float* W1r = (const float*)d_in[4];
    const float* b1r = (const float*)d_in[5];
    const float* W2r = (const float*)d_in[6];
    const float* b2r = (const float*)d_in[7];
    const float* W1c = (const float*)d_in[8];
    const float* b1c = (const float*)d_in[9];
    const float* W2c = (const float*)d_in[10];
    const float* b2c = (const float*)d_in[11];
    float* out = (float*)d_out;

    char* ws = (char*)d_ws;
    unsigned long long* scratch = (unsigned long long*)ws; ws += (size_t)NB * KK * NT * 8;
    int*   idxA   = (int*)ws;      ws += (size_t)NB * KK * 4;
    int*   minN   = (int*)ws;      ws += (size_t)NB * KK * 4;
    float* normA  = (float*)ws;    ws += (size_t)NB * KK * 4;
    float* resp   = (float*)ws;    ws += (size_t)NB * NF * 4;
    ushort_t* dFh = (ushort_t*)ws; ws += (size_t)NB * DFB * 2;
    ushort_t* dFl = (ushort_t*)ws; ws += (size_t)NB * DFB * 2;
    ushort_t* WFh = (ushort_t*)ws; ws += (size_t)COUT * 32 * 2;
    ushort_t* WFl = (ushort_t*)ws; ws += (size_t)COUT * 32 * 2;

    prep_kernel  <<<1, 256, 0, stream>>>(Wc, WFh, WFl);
    convA_kernel <<<dim3(256, NB), 256, 0, stream>>>(xA, WFh, WFl, bc, resp);
    select_kernel<<<NB * KK, 256, 0, stream>>>(resp, xA, Wc, bc, idxA, dFh, dFl, normA);
    fused_kernel <<<dim3(NT, NB), 256, 0, stream>>>(xB, WFh, WFl, bc, dFh, dFl,
                                                    normA, scratch);
    reduce_kernel<<<NB * KK, 64, 0, stream>>>(scratch, minN);
    mlp_kernel   <<<8, 128, 0, stream>>>(idxA, minN,
                                         W1r, b1r, W2r, b2r,
                                         W1c, b1c, W2c, b2c, out);
}

// Round 12
// 69.956 us; speedup vs baseline: 1.0119x; 1.0119x over previous
//
#include <hip/hip_runtime.h>
#include <stdint.h>

// ---- problem constants ----
constexpr int NB   = 4;      // batch
constexpr int CIN  = 3;
constexpr int HIN  = 256;
constexpr int COUT = 256;
constexpr int HF   = 128;              // feature H=W after stride-2 conv
constexpr int NF   = HF * HF;          // 16384
constexpr int KADM = 16;
constexpr int KK   = KADM * KADM;      // 256 descriptors
constexpr int HID  = 128;              // MLP hidden
constexpr int DFB  = 65536;            // desc-fragment u16s per batch
constexpr int PX   = 32;               // pixels per fused block
constexpr int NT   = NF / PX;          // 512 tiles per batch

typedef unsigned short ushort_t;
typedef __attribute__((ext_vector_type(8))) _Float16 f16x8;
typedef __attribute__((ext_vector_type(2))) __fp16   fp16v2;   // cvt_pkrtz result type
typedef __attribute__((ext_vector_type(4))) float    f32x4;

__device__ inline unsigned long long shfl_xor_u64(unsigned long long v, int m) {
    unsigned lo = __shfl_xor((unsigned)v, m, 64);
    unsigned hi = __shfl_xor((unsigned)(v >> 32), m, 64);
    return ((unsigned long long)hi << 32) | lo;
}
__device__ inline unsigned long long u64min(unsigned long long a, unsigned long long b) {
    return a < b ? a : b;
}
__device__ inline ushort_t f16bits(_Float16 h) { return __builtin_bit_cast(ushort_t, h); }

// LDS swizzle for [PX][256] f16 planes: XOR 8-f16 chunk index with pix&7.
__device__ inline int swz(int pix, int c) {
    return pix * 256 + ((((c >> 3) ^ (pix & 7)) << 3) | (c & 7));
}

// desc fragment address: [w][chunk][j][lane][8]
__device__ inline int dfoff(int w, int chunk, int j, int lane) {
    return (((w * 8 + chunk) * 4 + j) * 64 + lane) * 8;
}

// =====================================================================
// Prep: split conv weights into f16 hi/lo, K padded 27->32, stored in
// MFMA fragment order keyed by (w,j): co = w*64 + j*16 + la, k = lg*8+e.
// =====================================================================
__global__ __launch_bounds__(256) void prep_kernel(
        const float* __restrict__ W, ushort_t* __restrict__ WFh, ushort_t* __restrict__ WFl)
{
    int co = threadIdx.x;
    int w = co >> 6, j = (co >> 4) & 3, la = co & 15;
    #pragma unroll
    for (int q = 0; q < 32; ++q) {
        float v = (q < 27) ? W[co * 27 + q] : 0.f;
        _Float16 h = (_Float16)v;
        _Float16 l = (_Float16)(v - (float)h);
        int lg = q >> 3, e = q & 7;
        int off = ((w * 4 + j) * 64 + lg * 16 + la) * 8 + e;
        WFh[off] = f16bits(h);
        WFl[off] = f16bits(l);
    }
}

// =====================================================================
// Conv-A: MFMA im2col conv, emits resp = sum_c relu(v) only (64-px tiles).
// =====================================================================
__global__ __launch_bounds__(256) void convA_kernel(
        const float* __restrict__ xA,
        const ushort_t* __restrict__ WFh, const ushort_t* __restrict__ WFl,
        const float* __restrict__ bias, float* __restrict__ resp)
{
    __shared__ float    pS[CIN][3][132];
    __shared__ ushort_t Ah[64][40];
    __shared__ ushort_t Al[64][40];
    __shared__ float    redS[4][64];

    int tile = blockIdx.x;
    int b    = blockIdx.y;
    int oh   = tile >> 1;
    int ow0  = (tile & 1) << 6;
    const float* x = xA + (size_t)b * CIN * HIN * HIN;
    int tid = threadIdx.x;

    for (int i = tid; i < CIN * 3 * 129; i += 256) {
        int ci = i / (3 * 129);
        int r2 = i % (3 * 129);
        int kh = r2 / 129, c = r2 % 129;
        int gr = 2 * oh - 1 + kh, gc = 2 * ow0 - 1 + c;
        float v = 0.f;
        if (gr >= 0 && gr < HIN && gc >= 0 && gc < HIN)
            v = x[(size_t)ci * HIN * HIN + (size_t)gr * HIN + gc];
        pS[ci][kh][c] = v;
    }
    __syncthreads();

    {
        int n = tid >> 2, qg = tid & 3;
        unsigned uh[4], ul[4];
        #pragma unroll
        for (int e2 = 0; e2 < 4; ++e2) {
            ushort_t hh[2], ll[2];
            #pragma unroll
            for (int s = 0; s < 2; ++s) {
                int q = qg * 8 + e2 * 2 + s;
                float v = 0.f;
                if (q < 27) {
                    int ci = q / 9, r = (q % 9) / 3, kw = q % 3;
                    v = pS[ci][r][2 * n + kw];
                }
                _Float16 h = (_Float16)v;
                _Float16 l = (_Float16)(v - (float)h);
                hh[s] = f16bits(h); ll[s] = f16bits(l);
            }
            uh[e2] = (unsigned)hh[0] | ((unsigned)hh[1] << 16);
            ul[e2] = (unsigned)ll[0] | ((unsigned)ll[1] << 16);
        }
        *(uint4*)&Ah[n][qg * 8] = *(uint4*)uh;
        *(uint4*)&Al[n][qg * 8] = *(uint4*)ul;
    }
    __syncthreads();

    int lane = tid & 63, w = tid >> 6;
    int la = lane & 15, lg = lane >> 4;
    int wbase = w * 64;

    float bj[4];
    #pragma unroll
    for (int j = 0; j < 4; ++j) bj[j] = bias[wbase + j * 16 + la];

    f16x8 ah[4], al[4], bh[4], bl[4];
    #pragma unroll
    for (int i = 0; i < 4; ++i) {
        ah[i] = *(const f16x8*)&Ah[i * 16 + la][lg * 8];
        al[i] = *(const f16x8*)&Al[i * 16 + la][lg * 8];
    }
    #pragma unroll
    for (int j = 0; j < 4; ++j) {
        int off = ((w * 4 + j) * 64 + lane) * 8;
        bh[j] = *(const f16x8*)&WFh[off];
        bl[j] = *(const f16x8*)&WFl[off];
    }

    f32x4 acc[4][4];
    #pragma unroll
    for (int i = 0; i < 4; ++i)
        #pragma unroll
        for (int j = 0; j < 4; ++j) acc[i][j] = (f32x4)0.f;

    #pragma unroll
    for (int i = 0; i < 4; ++i)
        #pragma unroll
        for (int j = 0; j < 4; ++j) {
            acc[i][j] = __builtin_amdgcn_mfma_f32_16x16x32_f16(ah[i], bh[j], acc[i][j], 0, 0, 0);
            acc[i][j] = __builtin_amdgcn_mfma_f32_16x16x32_f16(al[i], bh[j], acc[i][j], 0, 0, 0);
            acc[i][j] = __builtin_amdgcn_mfma_f32_16x16x32_f16(ah[i], bl[j], acc[i][j], 0, 0, 0);
        }

    float s[4][4];
    #pragma unroll
    for (int i = 0; i < 4; ++i)
        #pragma unroll
        for (int r = 0; r < 4; ++r) s[i][r] = 0.f;

    #pragma unroll
    for (int i = 0; i < 4; ++i)
        #pragma unroll
        for (int j = 0; j < 4; ++j)
            #pragma unroll
            for (int r = 0; r < 4; ++r)
                s[i][r] += fmaxf(acc[i][j][r] + bj[j], 0.f);

    #pragma unroll
    for (int i = 0; i < 4; ++i)
        #pragma unroll
        for (int r = 0; r < 4; ++r) {
            float v = s[i][r];
            v += __shfl_xor(v, 1, 64);
            v += __shfl_xor(v, 2, 64);
            v += __shfl_xor(v, 4, 64);
            v += __shfl_xor(v, 8, 64);
            s[i][r] = v;
        }
    if (la == 0) {
        #pragma unroll
        for (int i = 0; i < 4; ++i)
            #pragma unroll
            for (int r = 0; r < 4; ++r)
                redS[w][i * 16 + lg * 4 + r] = s[i][r];
    }
    __syncthreads();
    if (tid < 64) {
        float tot = redS[0][tid] + redS[1][tid] + redS[2][tid] + redS[3][tid];
        resp[(size_t)b * NF + oh * HF + ow0 + tid] = tot;
    }
}

// =====================================================================
// Fused select: pool argmax (wave 0) + descriptor conv-recompute (fp32).
// Writes desc in MFMA B-fragment order: dFh/dFl[b][w][chunk][j][lane][8].
// =====================================================================
__global__ __launch_bounds__(256) void select_kernel(
        const float* __restrict__ resp,
        const float* __restrict__ xA, const float* __restrict__ W,
        const float* __restrict__ bias,
        int* __restrict__ idxA,
        ushort_t* __restrict__ dFh, ushort_t* __restrict__ dFl,
        float* __restrict__ normA)
{
    __shared__ float patch[27];
    __shared__ float red[4];
    __shared__ int   sidx;

    int bk = blockIdx.x;              // b*KK + k
    int b = bk >> 8, k = bk & 255;
    int t = threadIdx.x;              // channel c

    if (t < 64) {
        int kr = k >> 4, kc = k & 15;
        int lr = t >> 3, lc = t & 7;
        int row = kr * 8 + lr, col = kc * 8 + lc;
        float bv = resp[(size_t)b * NF + (size_t)row * HF + col];
        int best = t;
        for (int off = 32; off > 0; off >>= 1) {
            float ov = __shfl_down(bv, off, 64);
            int   oi = __shfl_down(best, off, 64);
            if (ov > bv || (ov == bv && oi < best)) { bv = ov; best = oi; }
        }
        if (t == 0) {
            int r = kr * 8 + (best >> 3), c = kc * 8 + (best & 7);
            int idx = r * HF + c;
            idxA[bk] = idx;
            sidx = idx;
        }
    }
    __syncthreads();
    int idx = sidx;
    int oh = idx >> 7, ow = idx & 127;

    if (t < 27) {
        int ci = t / 9, kh = (t % 9) / 3, kw = t % 3;
        int ir = oh * 2 - 1 + kh, ic = ow * 2 - 1 + kw;
        float v = 0.f;
        if (ir >= 0 && ir < HIN && ic >= 0 && ic < HIN)
            v = xA[((size_t)b * CIN + ci) * HIN * HIN + (size_t)ir * HIN + ic];
        patch[t] = v;
    }
    __syncthreads();

    float v = bias[t];
    const float* w = &W[t * 27];
    #pragma unroll
    for (int q = 0; q < 27; ++q) v = fmaf(patch[q], w[q], v);
    v = fmaxf(v, 0.f);

    _Float16 h = (_Float16)v;
    _Float16 l = (_Float16)(v - (float)h);
    {
        int wq = k >> 6, j = (k >> 4) & 3, la = k & 15;
        int chunk = t >> 5, lg = (t >> 3) & 3, e = t & 7;
        int off = b * DFB + dfoff(wq, chunk, j, lg * 16 + la) + e;
        dFh[off] = f16bits(h);
        dFl[off] = f16bits(l);
    }

    float s = v * v;
    for (int off = 32; off > 0; off >>= 1) s += __shfl_down(s, off, 64);
    if ((t & 63) == 0) red[t >> 6] = s;
    __syncthreads();
    if (t == 0) normA[bk] = red[0] + red[1] + red[2] + red[3];
}

// ---- fused-kernel helpers ----
__device__ inline void load_desc(const ushort_t* __restrict__ dFh,
                                 const ushort_t* __restrict__ dFl,
                                 int w, int chunk, int lane,
                                 f16x8* bh, f16x8* bl)
{
    #pragma unroll
    for (int j = 0; j < 4; ++j) {
        int off = dfoff(w, chunk, j, lane);
        bh[j] = *(const f16x8*)&dFh[off];
        bl[j] = *(const f16x8*)&dFl[off];
    }
}

__device__ inline void knn_chunk(const ushort_t* __restrict__ fH,
                                 const ushort_t* __restrict__ fL,
                                 int la, int lg, int cc,
                                 const f16x8* bh, const f16x8* bl,
                                 f32x4 (&acc)[2][4])
{
    #pragma unroll
    for (int i = 0; i < 2; ++i) {
        f16x8 ah = *(const f16x8*)&fH[swz(i * 16 + la, cc + lg * 8)];
        f16x8 al = *(const f16x8*)&fL[swz(i * 16 + la, cc + lg * 8)];
        __builtin_amdgcn_s_setprio(1);
        #pragma unroll
        for (int j = 0; j < 4; ++j) {
            acc[i][j] = __builtin_amdgcn_mfma_f32_16x16x32_f16(ah, bh[j], acc[i][j], 0, 0, 0);
            acc[i][j] = __builtin_amdgcn_mfma_f32_16x16x32_f16(al, bh[j], acc[i][j], 0, 0, 0);
            acc[i][j] = __builtin_amdgcn_mfma_f32_16x16x32_f16(ah, bl[j], acc[i][j], 0, 0, 0);
        }
        __builtin_amdgcn_s_setprio(0);
    }
}

// =====================================================================
// FUSED conv-B + kNN, 32-pixel blocks, 4 blocks/CU.
// Conv uses SWAPPED operands (A=weights M=channels, B=im2col N=pixels)
// so D gives each lane 4 CONSECUTIVE channels at one pixel -> epilogue
// is 16 swizzled ds_write_b64 (not 64 scattered b16).
// scratch layout [b][tile][k] -> wave writes 512B contiguous.
// =====================================================================
__global__ __launch_bounds__(256, 4) void fused_kernel(
        const float* __restrict__ xB,
        const ushort_t* __restrict__ WFh, const ushort_t* __restrict__ WFl,
        const float* __restrict__ bias,
        const ushort_t* __restrict__ dFhg, const ushort_t* __restrict__ dFlg,
        const float* __restrict__ normA,
        unsigned long long* __restrict__ scratch)
{
    __shared__ __align__(16) char smem[2 * PX * 256 * 2];   // 32768 B
    __shared__ float redS[4][PX];
    __shared__ float nAS[KK];
    __shared__ float nBS[PX];
    __shared__ float bS[COUT];

    float*    pSp = (float*)smem;                            // [3][3][68] = 2448B
    ushort_t* AhP = (ushort_t*)(smem + 2448);                // [32][40] = 2560B
    ushort_t* AlP = (ushort_t*)(smem + 2448 + 2560);         // [32][40]
    ushort_t* fH  = (ushort_t*)smem;                         // [PX][256] swizzled
    ushort_t* fL  = (ushort_t*)(smem + PX * 256 * 2);        // [PX][256] swizzled

    int tile = blockIdx.x;           // 0..511 (n-tile)
    int b    = blockIdx.y;
    int oh   = tile >> 2;
    int ow0  = (tile & 3) << 5;
    const float* x = xB + (size_t)b * CIN * HIN * HIN;
    int tid = threadIdx.x;

    nAS[tid] = normA[b * KK + tid];
    bS[tid]  = bias[tid];

    // ---- stage input rows: 3ci x 3kh x 65 cols ----
    for (int i = tid; i < CIN * 3 * 65; i += 256) {
        int ci = i / (3 * 65);
        int r2 = i % (3 * 65);
        int kh = r2 / 65, c = r2 % 65;
        int gr = 2 * oh - 1 + kh, gc = 2 * ow0 - 1 + c;
        float v = 0.f;
        if (gr >= 0 && gr < HIN && gc >= 0 && gc < HIN)
            v = x[(size_t)ci * HIN * HIN + (size_t)gr * HIN + gc];
        pSp[ci * 204 + kh * 68 + c] = v;
    }
    __syncthreads();

    // ---- im2col: n = tid>>3 (0..31), qg = tid&7 -> q = qg*4+s ----
    {
        int n = tid >> 3, qg = tid & 7;
        ushort_t hh[4], ll[4];
        #pragma unroll
        for (int s = 0; s < 4; ++s) {
            int q = qg * 4 + s;
            float v = 0.f;
            if (q < 27) {
                int ci = q / 9, r = (q % 9) / 3, kw = q % 3;
                v = pSp[ci * 204 + r * 68 + 2 * n + kw];
            }
            _Float16 h = (_Float16)v;
            _Float16 l = (_Float16)(v - (float)h);
            hh[s] = f16bits(h); ll[s] = f16bits(l);
        }
        unsigned lo, hi;
        lo = (unsigned)hh[0] | ((unsigned)hh[1] << 16);
        hi = (unsigned)hh[2] | ((unsigned)hh[3] << 16);
        *(uint2*)&AhP[n * 40 + qg * 4] = make_uint2(lo, hi);
        lo = (unsigned)ll[0] | ((unsigned)ll[1] << 16);
        hi = (unsigned)ll[2] | ((unsigned)ll[3] << 16);
        *(uint2*)&AlP[n * 40 + qg * 4] = make_uint2(lo, hi);
    }
    __syncthreads();

    int lane = tid & 63, w = tid >> 6;
    int la = lane & 15, lg = lane >> 4;
    int wbase = w * 64;

    // ---- conv MFMA, SWAPPED: A=weights (M=4 j ch-tiles), B=im2col (N=2 i px-tiles)
    f16x8 wah[4], wal[4], pbh[2], pbl[2];
    #pragma unroll
    for (int j = 0; j < 4; ++j) {
        int off = ((w * 4 + j) * 64 + lane) * 8;
        wah[j] = *(const f16x8*)&WFh[off];
        wal[j] = *(const f16x8*)&WFl[off];
    }
    #pragma unroll
    for (int i = 0; i < 2; ++i) {
        pbh[i] = *(const f16x8*)&AhP[(i * 16 + la) * 40 + lg * 8];
        pbl[i] = *(const f16x8*)&AlP[(i * 16 + la) * 40 + lg * 8];
    }

    f32x4 cacc[4][2];
    #pragma unroll
    for (int j = 0; j < 4; ++j)
        #pragma unroll
        for (int i = 0; i < 2; ++i) cacc[j][i] = (f32x4)0.f;

    #pragma unroll
    for (int j = 0; j < 4; ++j)
        #pragma unroll
        for (int i = 0; i < 2; ++i) {
            cacc[j][i] = __builtin_amdgcn_mfma_f32_16x16x32_f16(wah[j], pbh[i], cacc[j][i], 0, 0, 0);
            cacc[j][i] = __builtin_amdgcn_mfma_f32_16x16x32_f16(wal[j], pbh[i], cacc[j][i], 0, 0, 0);
            cacc[j][i] = __builtin_amdgcn_mfma_f32_16x16x32_f16(wah[j], pbl[i], cacc[j][i], 0, 0, 0);
        }

    __syncthreads();   // all waves done reading AhP/AlP (aliased with fH)

    // ---- epilogue: D lane = pixel i*16+la, channels wbase+j*16+lg*4+{0..3}
    float s2[2] = {0.f, 0.f};
    #pragma unroll
    for (int j = 0; j < 4; ++j) {
        f32x4 b4 = *(const f32x4*)&bS[wbase + j * 16 + lg * 4];
        int chunk = (wbase + j * 16 + lg * 4) >> 3;
        int within = (lg & 1) * 4;
        #pragma unroll
        for (int i = 0; i < 2; ++i) {
            int pix = i * 16 + la;
            float v0 = fmaxf(cacc[j][i][0] + b4[0], 0.f);
            float v1 = fmaxf(cacc[j][i][1] + b4[1], 0.f);
            float v2 = fmaxf(cacc[j][i][2] + b4[2], 0.f);
            float v3 = fmaxf(cacc[j][i][3] + b4[3], 0.f);
            s2[i] += v0 * v0 + v1 * v1 + v2 * v2 + v3 * v3;
            fp16v2 h01 = __builtin_amdgcn_cvt_pkrtz(v0, v1);
            fp16v2 h23 = __builtin_amdgcn_cvt_pkrtz(v2, v3);
            fp16v2 l01 = __builtin_amdgcn_cvt_pkrtz(v0 - (float)h01[0], v1 - (float)h01[1]);
            fp16v2 l23 = __builtin_amdgcn_cvt_pkrtz(v2 - (float)h23[0], v3 - (float)h23[1]);
            int base = pix * 256 + ((chunk ^ (pix & 7)) << 3) + within;
            *(uint2*)&fH[base] = make_uint2(__builtin_bit_cast(unsigned, h01),
                                            __builtin_bit_cast(unsigned, h23));
            *(uint2*)&fL[base] = make_uint2(__builtin_bit_cast(unsigned, l01),
                                            __builtin_bit_cast(unsigned, l23));
        }
    }

    // ---- early desc prefetch (cacc dead; loads fly under barrier/reduce) ----
    const ushort_t* dFh = dFhg + (size_t)b * DFB;
    const ushort_t* dFl = dFlg + (size_t)b * DFB;
    f16x8 bhA[4], blA[4], bhB[4], blB[4];
    load_desc(dFh, dFl, w, 0, lane, bhA, blA);
    load_desc(dFh, dFl, w, 1, lane, bhB, blB);

    // ---- normB: reduce s2 over lg lanes (same pixel la), then waves ----
    #pragma unroll
    for (int i = 0; i < 2; ++i) {
        float v = s2[i];
        v += __shfl_xor(v, 16, 64);
        v += __shfl_xor(v, 32, 64);
        if (lg == 0) redS[w][i * 16 + la] = v;
    }
    __syncthreads();
    if (tid < PX) nBS[tid] = redS[0][tid] + redS[1][tid] + redS[2][tid] + redS[3][tid];
    __syncthreads();

    // ---- kNN: 3-pass MFMA, 2-deep desc prefetch, no barriers ----
    f32x4 acc[2][4];
    #pragma unroll
    for (int i = 0; i < 2; ++i)
        #pragma unroll
        for (int j = 0; j < 4; ++j) acc[i][j] = (f32x4)0.f;

    knn_chunk(fH, fL, la, lg, 0, bhA, blA, acc);
    load_desc(dFh, dFl, w, 2, lane, bhA, blA);
    knn_chunk(fH, fL, la, lg, 32, bhB, blB, acc);
    load_desc(dFh, dFl, w, 3, lane, bhB, blB);
    knn_chunk(fH, fL, la, lg, 64, bhA, blA, acc);
    load_desc(dFh, dFl, w, 4, lane, bhA, blA);
    knn_chunk(fH, fL, la, lg, 96, bhB, blB, acc);
    load_desc(dFh, dFl, w, 5, lane, bhB, blB);
    knn_chunk(fH, fL, la, lg, 128, bhA, blA, acc);
    load_desc(dFh, dFl, w, 6, lane, bhA, blA);
    knn_chunk(fH, fL, la, lg, 160, bhB, blB, acc);
    load_desc(dFh, dFl, w, 7, lane, bhB, blB);
    knn_chunk(fH, fL, la, lg, 192, bhA, blA, acc);
    knn_chunk(fH, fL, la, lg, 224, bhB, blB, acc);

    // ---- epilogue: dist + per-k argmin; coalesced scratch write ----
    float nBv[2][4];
    #pragma unroll
    for (int i = 0; i < 2; ++i) {
        f32x4 t4 = *(const f32x4*)&nBS[i * 16 + lg * 4];
        nBv[i][0] = t4[0]; nBv[i][1] = t4[1]; nBv[i][2] = t4[2]; nBv[i][3] = t4[3];
    }
    int n0 = tile * PX;
    unsigned long long bestj[4];
    #pragma unroll
    for (int j = 0; j < 4; ++j) {
        int kl = wbase + j * 16 + la;
        float nAv = nAS[kl];
        unsigned long long best = ~0ull;
        #pragma unroll
        for (int i = 0; i < 2; ++i)
            #pragma unroll
            for (int r = 0; r < 4; ++r) {
                int n = n0 + i * 16 + lg * 4 + r;
                float d = fmaf(-2.f, acc[i][j][r], nAv) + nBv[i][r];
                unsigned u = __float_as_uint(d);
                u = (u & 0x80000000u) ? ~u : (u | 0x80000000u);
                unsigned long long key = ((unsigned long long)u << 32) | (unsigned)n;
                best = u64min(best, key);
            }
        best = u64min(best, shfl_xor_u64(best, 16));
        best = u64min(best, shfl_xor_u64(best, 32));
        bestj[j] = best;
    }
    // every lane writes one k: kl = wbase + lg*16 + la (contiguous per wave)
    unsigned long long key = (lg == 0) ? bestj[0] : (lg == 1) ? bestj[1]
                           : (lg == 2) ? bestj[2] : bestj[3];
    int klw = wbase + lg * 16 + la;
    scratch[((size_t)b * NT + tile) * KK + klw] = key;
}

// =====================================================================
// Final argmin reduce over NT tiles, scratch layout [b][tile][k].
// grid (8, NB): block handles 32 k's; threads = 8 tiles x 32 k.
// =====================================================================
__global__ __launch_bounds__(256) void reduce_kernel(
        const unsigned long long* __restrict__ scratch, int* __restrict__ minN)
{
    __shared__ unsigned long long part[8][32];
    int g = blockIdx.x;               // 0..7 (k-group)
    int b = blockIdx.y;
    int t = threadIdx.x;
    int ts = t >> 5, kk = t & 31;
    int k = g * 32 + kk;

    unsigned long long best = ~0ull;
    #pragma unroll 4
    for (int m = 0; m < NT / 8; ++m) {
        int tile = m * 8 + ts;
        best = u64min(best, scratch[((size_t)b * NT + tile) * KK + k]);
    }
    part[ts][kk] = best;
    __syncthreads();
    if (t < 32) {
        unsigned long long x = part[0][t];
        #pragma unroll
        for (int p = 1; p < 8; ++p) x = u64min(x, part[p][t]);
        minN[b * KK + g * 32 + t] = (int)(x & 0xffffffffULL);
    }
}

// =====================================================================
// Two tiny MLPs: x(256) -> 128 relu -> 1. block per (b, which), 128 threads.
// =====================================================================
__global__ __launch_bounds__(128) void mlp_kernel(
        const int* __restrict__ idxA, const int* __restrict__ minN,
        const float* __restrict__ W1r, const float* __restrict__ b1r,
        const float* __restrict__ W2r, const float* __restrict__ b2r,
        const float* __restrict__ W1c, const float* __restrict__ b1c,
        const float* __restrict__ W2c, const float* __restrict__ b2c,
        float* __restrict__ out)
{
    __shared__ float xS[KK];
    __shared__ float red[2];
    int blk = blockIdx.x;            // b*2 + which
    int b = blk >> 1, which = blk & 1;
    int t = threadIdx.x;             // 0..127

    for (int k = t; k < KK; k += 128) {
        int ia = idxA[b * KK + k];
        int nn = minN[b * KK + k];
        int rowA = ia >> 7, colA = ia & 127;
        int rowB = nn >> 7, colB = nn & 127;
        xS[k] = (which == 0) ? (float)(rowB - rowA) : (float)(colA - colB);
    }
    __syncthreads();

    const float* W1 = which ? W1c : W1r;
    const float* b1 = which ? b1c : b1r;
    const float* W2 = which ? W2c : W2r;
    const float* b2 = which ? b2c : b2r;

    float h = b1[t];
    for (int k = 0; k < KK; ++k) h = fmaf(xS[k], W1[k * HID + t], h);
    h = fmaxf(h, 0.f);
    float pv = h * W2[t];
    for (int off = 32; off > 0; off >>= 1) pv += __shfl_down(pv, off, 64);
    if ((t & 63) == 0) red[t >> 6] = pv;
    __syncthreads();
    if (t == 0) out[b * 2 + which] = red[0] + red[1] + b2[0];
}

// =====================================================================
extern "C" void kernel_launch(void* const* d_in, const int* in_sizes, int n_in,
                              void* d_out, int out_size, void* d_ws, size_t ws_size,
                              hipStream_t stream)
{
    const float* xA  = (const float*)d_in[0];
    const float* xB  = (const float*)d_in[1];
    const float* Wc  = (const float*)d_in[2];
    const float* bc  = (const float*)d_in[3];
    const float* W1r = (const float*)d_in[4];
    const float* b1r = (const float*)d_in[5];
    const float* W2r = (const float*)d_in[6];
    const float* b2r = (const float*)d_in[7];
    const float* W1c = (const float*)d_in[8];
    const float* b1c = (const float*)d_in[9];
    const float* W2c = (const float*)d_in[10];
    const float* b2c = (const float*)d_in[11];
    float* out = (float*)d_out;

    char* ws = (char*)d_ws;
    unsigned long long* scratch = (unsigned long long*)ws; ws += (size_t)NB * KK * NT * 8;
    int*   idxA   = (int*)ws;      ws += (size_t)NB * KK * 4;
    int*   minN   = (int*)ws;      ws += (size_t)NB * KK * 4;
    float* normA  = (float*)ws;    ws += (size_t)NB * KK * 4;
    float* resp   = (float*)ws;    ws += (size_t)NB * NF * 4;
    ushort_t* dFh = (ushort_t*)ws; ws += (size_t)NB * DFB * 2;
    ushort_t* dFl = (ushort_t*)ws; ws += (size_t)NB * DFB * 2;
    ushort_t* WFh = (ushort_t*)ws; ws += (size_t)COUT * 32 * 2;
    ushort_t* WFl = (ushort_t*)ws; ws += (size_t)COUT * 32 * 2;

    prep_kernel  <<<1, 256, 0, stream>>>(Wc, WFh, WFl);
    convA_kernel <<<dim3(256, NB), 256, 0, stream>>>(xA, WFh, WFl, bc, resp);
    select_kernel<<<NB * KK, 256, 0, stream>>>(resp, xA, Wc, bc, idxA, dFh, dFl, normA);
    fused_kernel <<<dim3(NT, NB), 256, 0, stream>>>(xB, WFh, WFl, bc, dFh, dFl,
                                                    normA, scratch);
    reduce_kernel<<<dim3(8, NB), 256, 0, stream>>>(scratch, minN);
    mlp_kernel   <<<8, 128, 0, stream>>>(idxA, minN,
                                         W1r, b1r, W2r, b2r,
                                         W1c, b1c, W2c, b2c, out);
}